// Round 2
// baseline (652.444 us; speedup 1.0000x reference)
//
#include <hip/hip_runtime.h>
#include <stdint.h>

#define BSZB 256

constexpr int BB = 8;       // batch
constexpr int NN = 2048;    // neurons
constexpr int KK = 32;      // connections
constexpr int DD = 64;      // dim
constexpr int HH = 128;     // hidden (all three MLPs)
constexpr int SIN = 164;    // s_in row stride (161 rounded to x4 -> 16B-aligned rows)

__device__ __forceinline__ float sigmoidf_(float x) { return 1.0f / (1.0f + expf(-x)); }

// Layer-1 GEMM: s_hid[b][h] = tanh( sum_i s_in[b][i]*W[h][i] + bias[h] ),
// 128 h-rows processed as 4 tiles of 32. One output per thread: hl=t&31, b=t>>5.
//
// WSTRIDE==L (odd L: 161/129): LINEAR LDS tile, staged as float4 global->float4 LDS
//   (flat word e -> LDS word e; both sides 16B aligned, coalesced, conflict-free).
//   Read banks: (hl*L + i)%32 = (hl+i)%32 since L%32==1 -> 32 distinct banks, balanced.
// WSTRIDE!=L (L=128 -> pad 129): reg-staged per-element (linear 128 would put all
//   lanes of a read in one bank = 32-way conflict).
//
// Input row read as float4 (s_in stride 164 -> aligned); uniform per 32-lane half
// -> LDS broadcast. Per 4 i: 4x ds_read_b32 (w) + 1x ds_read_b128 (in).
template<int L, int WSTRIDE>
__device__ __forceinline__ void gemmA(const float* __restrict__ Wg,
                                      const float* __restrict__ bias,
                                      const float* s_in, float* s_w, float* s_hid,
                                      int t)
{
    const int hl = t & 31;
    const int b  = t >> 5;
    #pragma unroll 1
    for (int tile = 0; tile < 4; ++tile) {
        const float* wt = Wg + tile * 32 * L;
        if constexpr (WSTRIDE == L) {
            constexpr int nvec = (32 * L) / 4;          // 32*L % 4 == 0
            for (int v = t; v < nvec; v += BSZB)
                *(float4*)(s_w + v * 4) = *(const float4*)(wt + v * 4);
        } else {
            constexpr int elems = 32 * L;               // L%4==0 here (L=128)
            #pragma unroll
            for (int it = 0; it < elems / (BSZB * 4); ++it) {
                int e = t * 4 + it * (BSZB * 4);
                float4 v = *(const float4*)(wt + e);
                int hr = e >> 7, c = e & 127;           // rows never straddled (128%4==0)
                float* dst = s_w + hr * WSTRIDE + c;
                dst[0] = v.x; dst[1] = v.y; dst[2] = v.z; dst[3] = v.w;
            }
        }
        __syncthreads();
        const float* wr = s_w + hl * WSTRIDE;
        const float* ir = s_in + b * SIN;
        float a0 = 0.f, a1 = 0.f, a2 = 0.f, a3 = 0.f;
        constexpr int L4 = L & ~3;
        #pragma unroll 4
        for (int i = 0; i < L4; i += 4) {
            float4 iv = *(const float4*)(ir + i);       // ds_read_b128, broadcast
            a0 += wr[i+0] * iv.x;
            a1 += wr[i+1] * iv.y;
            a2 += wr[i+2] * iv.z;
            a3 += wr[i+3] * iv.w;
        }
        if constexpr (L4 < L) {
            #pragma unroll
            for (int i = L4; i < L; ++i) a0 += wr[i] * ir[i];
        }
        float acc = (a0 + a1) + (a2 + a3);
        int hg = tile * 32 + hl;
        s_hid[b * HH + hg] = tanhf(acc + bias[hg]);
        __syncthreads();                                // s_w reusable next tile
    }
}

__global__ __launch_bounds__(BSZB, 4) void memgraph_kernel(
    const float* __restrict__ g_h,   const float* __restrict__ g_pm,
    const float* __restrict__ g_heb, const float* __restrict__ g_dlog,
    const float* __restrict__ g_prim,
    const float* __restrict__ mw1, const float* __restrict__ mb1,
    const float* __restrict__ mw2, const float* __restrict__ mb2,
    const float* __restrict__ sw1, const float* __restrict__ sb1,
    const float* __restrict__ sw2, const float* __restrict__ sb2,
    const float* __restrict__ xw1, const float* __restrict__ xb1,
    const float* __restrict__ xw2, const float* __restrict__ xb2,
    const float* __restrict__ dbw, const float* __restrict__ dgw,
    const int* __restrict__ conn, float* __restrict__ out)
{
    const int n = blockIdx.x;
    const int t = threadIdx.x;

    __shared__ float s_w[32 * 161];     // weight tile: max(32*161, 32*129) = 20.6 KB
    __shared__ float s_in[BB * SIN];    // MLP input rows (mod_in / sx / mx), stride 164
    __shared__ float s_hid[BB * HH];    // hidden activations
    __shared__ float s_hc[BB * DD];     // cached h (reused for sx)
    __shared__ float s_wsig[BB * KK];   // sigmoid(new_w_conn)
    __shared__ float s_np[BB * DD];     // new_primitives (raw)
    __shared__ float s_dec[BB];         // sigmoid(new_decay_logit)
    __shared__ float s_recv[BB * DD];   // dendrite output
    __shared__ float s_hnew[BB * DD];   // h_new
    __shared__ int   s_conn[KK];
    // total 39,328 B -> 4 blocks/CU (40 KB budget)

    // ---- P0: mod_in = [heb(32) | h(64) | decay_logit(1) | prim(64)] ----
    {
        int b = t >> 5, k = t & 31;
        s_in[b * SIN + k] = g_heb[(b * NN + n) * KK + k];
        #pragma unroll
        for (int r = 0; r < 2; ++r) {
            int e = t + r * BSZB, bb = e >> 6, d = e & 63;
            float hv = g_h[(bb * NN + n) * DD + d];
            s_in[bb * SIN + 32 + d] = hv;
            s_hc[bb * DD + d] = hv;
            s_in[bb * SIN + 97 + d] = g_prim[(bb * NN + n) * DD + d];
        }
        if (t < BB) s_in[t * SIN + 96] = g_dlog[t * NN + n];
        if (t < KK) s_conn[t] = conn[n * KK + t];
    }
    __syncthreads();

    // ---- P1: mod layer 1 (L=161) ----
    gemmA<161, 161>(mw1 + (size_t)n * HH * 161, mb1 + n * HH, s_in, s_w, s_hid, t);

    // ---- P2: mod layer 2 (97 outputs), weights direct-coalesced from global ----
    {
        const float* w2 = mw2 + (size_t)n * HH * 97;
        int o = t & 127, bg = t >> 7;                   // 2 groups x 4 batches
        if (o < 97) {
            const float* hs = s_hid + (bg * 4) * HH;
            float a[4] = {0.f, 0.f, 0.f, 0.f};
            #pragma unroll 4
            for (int hq = 0; hq < HH / 4; ++hq) {
                float wv[4];
                #pragma unroll
                for (int j = 0; j < 4; ++j) wv[j] = w2[(hq * 4 + j) * 97 + o];
                #pragma unroll
                for (int bb2 = 0; bb2 < 4; ++bb2) {
                    float hv[4];
                    *(float4*)hv = *(const float4*)(hs + bb2 * HH + hq * 4);
                    #pragma unroll
                    for (int j = 0; j < 4; ++j) a[bb2] += hv[j] * wv[j];
                }
            }
            float bv = mb2[n * 97 + o];
            #pragma unroll
            for (int j = 0; j < 4; ++j) {
                int b = bg * 4 + j; float v = a[j] + bv;
                if (o < KK)        s_wsig[b * KK + o] = sigmoidf_(v);
                else if (o == KK)  s_dec[b] = sigmoidf_(v);
                else               s_np[b * DD + o - KK - 1] = v;
            }
        }
    }
    __syncthreads();

    // ---- P3: gather + dendrite tree, barrier-free (thread = (b,d), 2 passes) ----
    {
        int d = t & 63;
        #pragma unroll 1
        for (int pass = 0; pass < 2; ++pass) {
            int b = pass * 4 + (t >> 6);
            float gsum = 0.f;
            #pragma unroll
            for (int br = 0; br < 4; ++br) {
                float acc = 0.f;
                #pragma unroll
                for (int s = 0; s < 8; ++s) {
                    int ci = s_conn[br * 8 + s];                       // broadcast
                    float m = g_pm[((size_t)b * NN + ci) * DD + d];    // 256B coalesced
                    acc += m * s_wsig[b * KK + br * 8 + s]
                             * dbw[(size_t)n * 2048 + (br * 8 + s) * DD + d];
                }
                gsum += tanhf(acc) * dgw[(size_t)n * 256 + br * DD + d];
            }
            s_recv[b * DD + d] = tanhf(gsum);           // mean over NG=1 == identity
        }
    }
    __syncthreads();

    // ---- P4: sx = [received(64) | h(64) | decay(1)] ----
    {
        #pragma unroll
        for (int r = 0; r < 2; ++r) {
            int e = t + r * BSZB, b = e >> 6, d = e & 63;
            s_in[b * SIN + d]      = s_recv[b * DD + d];
            s_in[b * SIN + 64 + d] = s_hc[b * DD + d];
        }
        if (t < BB) s_in[t * SIN + 128] = s_dec[t];
    }
    __syncthreads();

    // ---- state layer 1 (L=129) ----
    gemmA<129, 129>(sw1 + (size_t)n * HH * 129, sb1 + n * HH, s_in, s_w, s_hid, t);

    // ---- P5: h_new = tanh(sh @ state_w2 + b2); output slot 0 ----
    {
        const float* w = sw2 + (size_t)n * HH * DD;
        int d = t & 63, bg = t >> 6;                    // 4 groups x 2 batches
        const float* h0 = s_hid + (bg * 2 + 0) * HH;
        const float* h1 = s_hid + (bg * 2 + 1) * HH;
        float a0 = 0.f, a1 = 0.f;
        #pragma unroll 4
        for (int hq = 0; hq < HH / 4; ++hq) {
            float hv0[4], hv1[4];
            *(float4*)hv0 = *(const float4*)(h0 + hq * 4);
            *(float4*)hv1 = *(const float4*)(h1 + hq * 4);
            #pragma unroll
            for (int j = 0; j < 4; ++j) {
                float wv = w[(hq * 4 + j) * DD + d];    // coalesced
                a0 += hv0[j] * wv; a1 += hv1[j] * wv;
            }
        }
        float bv = sb2[n * DD + d];
        float v0 = tanhf(a0 + bv), v1 = tanhf(a1 + bv);
        s_hnew[(bg * 2 + 0) * DD + d] = v0;
        s_hnew[(bg * 2 + 1) * DD + d] = v1;
        out[((size_t)(bg * 2 + 0) * NN + n) * DD + d] = v0;
        out[((size_t)(bg * 2 + 1) * NN + n) * DD + d] = v1;
    }
    __syncthreads();

    // ---- P6: mx = [h_new(64) | new_primitives(64)] ----
    {
        #pragma unroll
        for (int r = 0; r < 2; ++r) {
            int e = t + r * BSZB, b = e >> 6, d = e & 63;
            s_in[b * SIN + d]      = s_hnew[b * DD + d];
            s_in[b * SIN + 64 + d] = s_np[b * DD + d];
        }
    }
    __syncthreads();

    // ---- msg layer 1 (L=128 -> padded stride 129, reg-staged) ----
    gemmA<128, 129>(xw1 + (size_t)n * HH * 128, xb1 + n * HH, s_in, s_w, s_hid, t);

    // ---- P7: msg = tanh(mh @ msg_w2 + b2); output slot 1 ----
    {
        const float* w = xw2 + (size_t)n * HH * DD;
        int d = t & 63, bg = t >> 6;
        const float* h0 = s_hid + (bg * 2 + 0) * HH;
        const float* h1 = s_hid + (bg * 2 + 1) * HH;
        float a0 = 0.f, a1 = 0.f;
        #pragma unroll 4
        for (int hq = 0; hq < HH / 4; ++hq) {
            float hv0[4], hv1[4];
            *(float4*)hv0 = *(const float4*)(h0 + hq * 4);
            *(float4*)hv1 = *(const float4*)(h1 + hq * 4);
            #pragma unroll
            for (int j = 0; j < 4; ++j) {
                float wv = w[(hq * 4 + j) * DD + d];
                a0 += hv0[j] * wv; a1 += hv1[j] * wv;
            }
        }
        float bv = xb2[n * DD + d];
        size_t base = (size_t)BB * NN * DD;
        out[base + ((size_t)(bg * 2 + 0) * NN + n) * DD + d] = tanhf(a0 + bv);
        out[base + ((size_t)(bg * 2 + 1) * NN + n) * DD + d] = tanhf(a1 + bv);
    }
}

extern "C" void kernel_launch(void* const* d_in, const int* in_sizes, int n_in,
                              void* d_out, int out_size, void* d_ws, size_t ws_size,
                              hipStream_t stream) {
    memgraph_kernel<<<dim3(NN), dim3(BSZB), 0, stream>>>(
        (const float*)d_in[0],  (const float*)d_in[1],  (const float*)d_in[2],
        (const float*)d_in[3],  (const float*)d_in[4],  (const float*)d_in[5],
        (const float*)d_in[6],  (const float*)d_in[7],  (const float*)d_in[8],
        (const float*)d_in[9],  (const float*)d_in[10], (const float*)d_in[11],
        (const float*)d_in[12], (const float*)d_in[13], (const float*)d_in[14],
        (const float*)d_in[15], (const float*)d_in[16], (const float*)d_in[17],
        (const float*)d_in[18], (const int*)d_in[19],   (float*)d_out);
}